// Round 1
// baseline (349.012 us; speedup 1.0000x reference)
//
#include <hip/hip_runtime.h>
#include <stdint.h>

// MHA: B=2, S=2048, DIM=1024, H=16, HD=64, causal, fp32 I/O, bf16 MFMA internal.
// Pipeline: proj3 (q,k,v @ w.T -> bf16 Xq/Xk/Xv) -> flash_attn -> out gemm (fp32 out).

typedef short s16x8 __attribute__((ext_vector_type(8)));
typedef float f32x4 __attribute__((ext_vector_type(4)));

#define MFMA_BF16 __builtin_amdgcn_mfma_f32_16x16x32_bf16

__device__ __forceinline__ unsigned short f2bf(float f) {
    union { float f; unsigned u; } x{f};
    unsigned r = x.u + 0x7fff + ((x.u >> 16) & 1);   // RNE
    return (unsigned short)(r >> 16);
}
__device__ __forceinline__ unsigned pk2(float a, float b) {
    return (unsigned)f2bf(a) | ((unsigned)f2bf(b) << 16);
}

// ---------------------------------------------------------------------------
// GEMM body: C[M=4096 x N=1024] = A[4096 x 1024] @ Bt[1024 x 1024]^T
// Bt given row-major [N,K] (torch Linear weight layout) == B^T form.
// 128x128 block tile, BK=32, 4 waves each 64x64, 16x16x32 bf16 MFMA.
// ---------------------------------------------------------------------------
template <bool ABF16, bool OUTBF16>
__device__ __forceinline__ void gemm_body(const void* __restrict__ Ap,
                                          const float* __restrict__ Bt,
                                          void* __restrict__ Cp) {
    constexpr int Kd = 1024, Nd = 1024;
    __shared__ unsigned short lsA[128][40];   // rows 80B: 16B-aligned, 2-way bank alias (free)
    __shared__ unsigned short lsB[128][40];

    const int t    = threadIdx.x;
    const int m0   = blockIdx.y * 128;
    const int n0   = blockIdx.x * 128;
    const int srow = t >> 1;            // 0..127
    const int scol = (t & 1) * 16;      // 0 / 16
    const int w    = t >> 6;
    const int lane = t & 63;
    const int wm   = (w >> 1) * 64;
    const int wn   = (w & 1) * 64;
    const int fr   = lane & 15;
    const int g    = lane >> 4;
    const int fq   = g * 8;

    f32x4 acc[4][4] = {};

    for (int k0 = 0; k0 < Kd; k0 += 32) {
        // ---- stage A tile [128 x 32] as bf16 ----
        if (ABF16) {
            const uint4* pa = (const uint4*)((const unsigned short*)Ap +
                               (size_t)(m0 + srow) * Kd + k0 + scol);
            uint4 u0 = pa[0], u1 = pa[1];
            *(uint4*)&lsA[srow][scol]     = u0;
            *(uint4*)&lsA[srow][scol + 8] = u1;
        } else {
            const float4* pa = (const float4*)((const float*)Ap +
                                (size_t)(m0 + srow) * Kd + k0 + scol);
            float4 a0 = pa[0], a1 = pa[1], a2 = pa[2], a3 = pa[3];
            uint4 u0, u1;
            u0.x = pk2(a0.x, a0.y); u0.y = pk2(a0.z, a0.w);
            u0.z = pk2(a1.x, a1.y); u0.w = pk2(a1.z, a1.w);
            u1.x = pk2(a2.x, a2.y); u1.y = pk2(a2.z, a2.w);
            u1.z = pk2(a3.x, a3.y); u1.w = pk2(a3.z, a3.w);
            *(uint4*)&lsA[srow][scol]     = u0;
            *(uint4*)&lsA[srow][scol + 8] = u1;
        }
        // ---- stage B tile [128 x 32] as bf16 (always fp32 weights) ----
        {
            const float4* pb = (const float4*)(Bt + (size_t)(n0 + srow) * Kd + k0 + scol);
            float4 b0 = pb[0], b1 = pb[1], b2 = pb[2], b3 = pb[3];
            uint4 u0, u1;
            u0.x = pk2(b0.x, b0.y); u0.y = pk2(b0.z, b0.w);
            u0.z = pk2(b1.x, b1.y); u0.w = pk2(b1.z, b1.w);
            u1.x = pk2(b2.x, b2.y); u1.y = pk2(b2.z, b2.w);
            u1.z = pk2(b3.x, b3.y); u1.w = pk2(b3.z, b3.w);
            *(uint4*)&lsB[srow][scol]     = u0;
            *(uint4*)&lsB[srow][scol + 8] = u1;
        }
        __syncthreads();

        s16x8 af[4], bfr[4];
#pragma unroll
        for (int mi = 0; mi < 4; ++mi)
            af[mi] = *(const s16x8*)&lsA[wm + mi * 16 + fr][fq];
#pragma unroll
        for (int ni = 0; ni < 4; ++ni)
            bfr[ni] = *(const s16x8*)&lsB[wn + ni * 16 + fr][fq];
#pragma unroll
        for (int mi = 0; mi < 4; ++mi)
#pragma unroll
            for (int ni = 0; ni < 4; ++ni)
                acc[mi][ni] = MFMA_BF16(af[mi], bfr[ni], acc[mi][ni], 0, 0, 0);
        __syncthreads();
    }

    // ---- epilogue: C/D layout col=lane&15, row=g*4+reg ----
#pragma unroll
    for (int mi = 0; mi < 4; ++mi) {
#pragma unroll
        for (int ni = 0; ni < 4; ++ni) {
#pragma unroll
            for (int reg = 0; reg < 4; ++reg) {
                const int gm = m0 + wm + mi * 16 + g * 4 + reg;
                const int gn = n0 + wn + ni * 16 + fr;
                if (OUTBF16)
                    ((unsigned short*)Cp)[(size_t)gm * Nd + gn] = f2bf(acc[mi][ni][reg]);
                else
                    ((float*)Cp)[(size_t)gm * Nd + gn] = acc[mi][ni][reg];
            }
        }
    }
}

// Fused q/k/v projections: grid (8, 32, 3)
__global__ __launch_bounds__(256) void proj3_kernel(
        const float* __restrict__ q,  const float* __restrict__ k,  const float* __restrict__ v,
        const float* __restrict__ wq, const float* __restrict__ wk, const float* __restrict__ wv,
        unsigned short* __restrict__ xq, unsigned short* __restrict__ xk,
        unsigned short* __restrict__ xv) {
    const int z = blockIdx.z;
    const float* A  = (z == 0) ? q  : (z == 1) ? k  : v;
    const float* Bt = (z == 0) ? wq : (z == 1) ? wk : wv;
    unsigned short* C = (z == 0) ? xq : (z == 1) ? xk : xv;
    gemm_body<false, true>(A, Bt, C);
}

// Output projection: fp32 result. grid (8, 32)
__global__ __launch_bounds__(256) void outproj_kernel(
        const unsigned short* __restrict__ Oa, const float* __restrict__ wo,
        float* __restrict__ out) {
    gemm_body<true, false>(Oa, wo, out);
}

// ---------------------------------------------------------------------------
// Flash attention, causal. Xq/Xk/Xv: [4096 x 1024] bf16, token-major, head slice
// at col h*64. grid (32 qtiles, 32 b*h), block 256 = 4 waves, wave owns 16 q rows.
// ---------------------------------------------------------------------------
__global__ __launch_bounds__(256) void flash_attn_kernel(
        const unsigned short* __restrict__ Xq, const unsigned short* __restrict__ Xk,
        const unsigned short* __restrict__ Xv, unsigned short* __restrict__ Oa) {
    __shared__ unsigned short Kls[64][72];     // [key][d]   144B rows
    __shared__ unsigned short Vt[64][72];      // [d][key]   transposed
    __shared__ unsigned short Pls[4][16][72];  // per-wave P [q][key]

    const int t    = threadIdx.x;
    const int qt   = blockIdx.x;               // 0..31
    const int bh   = blockIdx.y;               // 0..31
    const int b    = bh >> 4;
    const int h    = bh & 15;
    const size_t rbase = (size_t)b * 2048;
    const int cbase = h * 64;

    const int w    = t >> 6;
    const int lane = t & 63;
    const int fr   = lane & 15;
    const int g    = lane >> 4;
    const int fq   = g * 8;

    // staging coords
    const int sr = t >> 2;            // 0..63 (row within tile)
    const int sc = (t & 3) * 16;      // 0/16/32/48

    // Q fragments (A-layout): rows qt*64 + w*16 + fr, k = kc*32 + fq + j
    const unsigned short* qp = Xq + (rbase + qt * 64 + w * 16 + fr) * 1024 + cbase;
    s16x8 aq0 = *(const s16x8*)(qp + fq);
    s16x8 aq1 = *(const s16x8*)(qp + 32 + fq);

    float mrow[4], lrow[4];
    f32x4 oacc[4] = {};
#pragma unroll
    for (int r = 0; r < 4; ++r) { mrow[r] = -1e30f; lrow[r] = 0.f; }

    for (int kt = 0; kt <= qt; ++kt) {
        // ---- stage K tile [64 keys x 64 d] and V^T tile ----
        {
            const unsigned short* kp = Xk + (rbase + kt * 64 + sr) * 1024 + cbase + sc;
            uint4 k0 = *(const uint4*)kp;
            uint4 k1 = *(const uint4*)(kp + 8);
            *(uint4*)&Kls[sr][sc]     = k0;
            *(uint4*)&Kls[sr][sc + 8] = k1;

            const unsigned short* vp = Xv + (rbase + kt * 64 + sr) * 1024 + cbase + sc;
            uint4 v0 = *(const uint4*)vp;
            uint4 v1 = *(const uint4*)(vp + 8);
            unsigned short tmp[16];
            *(uint4*)tmp       = v0;
            *(uint4*)(tmp + 8) = v1;
#pragma unroll
            for (int i = 0; i < 16; ++i) Vt[sc + i][sr] = tmp[i];
        }
        __syncthreads();

        // ---- S = Q @ K^T : 4 frags of [16q x 16key] ----
        f32x4 sf[4] = {};
#pragma unroll
        for (int n16 = 0; n16 < 4; ++n16) {
            s16x8 kf0 = *(const s16x8*)&Kls[n16 * 16 + fr][fq];
            s16x8 kf1 = *(const s16x8*)&Kls[n16 * 16 + fr][32 + fq];
            sf[n16] = MFMA_BF16(aq0, kf0, sf[n16], 0, 0, 0);
            sf[n16] = MFMA_BF16(aq1, kf1, sf[n16], 0, 0, 0);
        }

        // ---- scale, causal mask, online softmax ----
        float p[4][4];     // [n16][reg]
        float mx[4], alpha[4], psum[4];
#pragma unroll
        for (int reg = 0; reg < 4; ++reg) {
            const int qg = qt * 64 + w * 16 + g * 4 + reg;   // global q
            float mreg = -1e30f;
#pragma unroll
            for (int n16 = 0; n16 < 4; ++n16) {
                const int kg = kt * 64 + n16 * 16 + fr;      // global key
                float x = sf[n16][reg] * 0.125f;
                x = (kg <= qg) ? x : -1e30f;
                p[n16][reg] = x;
                mreg = fmaxf(mreg, x);
            }
            mx[reg] = mreg;
        }
#pragma unroll
        for (int off = 1; off < 16; off <<= 1)
#pragma unroll
            for (int reg = 0; reg < 4; ++reg)
                mx[reg] = fmaxf(mx[reg], __shfl_xor(mx[reg], off, 64));
#pragma unroll
        for (int reg = 0; reg < 4; ++reg) {
            const float mn = fmaxf(mrow[reg], mx[reg]);
            alpha[reg] = __expf(mrow[reg] - mn);
            mrow[reg] = mn;
            float sum = 0.f;
#pragma unroll
            for (int n16 = 0; n16 < 4; ++n16) {
                const float e = __expf(p[n16][reg] - mn);
                p[n16][reg] = e;
                sum += e;
            }
            psum[reg] = sum;
        }
#pragma unroll
        for (int off = 1; off < 16; off <<= 1)
#pragma unroll
            for (int reg = 0; reg < 4; ++reg)
                psum[reg] += __shfl_xor(psum[reg], off, 64);
#pragma unroll
        for (int reg = 0; reg < 4; ++reg)
            lrow[reg] = lrow[reg] * alpha[reg] + psum[reg];
#pragma unroll
        for (int n = 0; n < 4; ++n)
#pragma unroll
            for (int reg = 0; reg < 4; ++reg)
                oacc[n][reg] *= alpha[reg];

        // ---- P: C-layout -> A-layout via per-wave LDS ----
#pragma unroll
        for (int n16 = 0; n16 < 4; ++n16)
#pragma unroll
            for (int reg = 0; reg < 4; ++reg)
                Pls[w][g * 4 + reg][n16 * 16 + fr] = f2bf(p[n16][reg]);

        s16x8 pa0 = *(const s16x8*)&Pls[w][fr][fq];
        s16x8 pa1 = *(const s16x8*)&Pls[w][fr][32 + fq];

        // ---- O += P @ V ----
#pragma unroll
        for (int n = 0; n < 4; ++n) {
            s16x8 vb0 = *(const s16x8*)&Vt[n * 16 + fr][fq];
            s16x8 vb1 = *(const s16x8*)&Vt[n * 16 + fr][32 + fq];
            oacc[n] = MFMA_BF16(pa0, vb0, oacc[n], 0, 0, 0);
            oacc[n] = MFMA_BF16(pa1, vb1, oacc[n], 0, 0, 0);
        }
        __syncthreads();
    }

    // ---- epilogue: O /= l, store bf16 ----
    float inv[4];
#pragma unroll
    for (int reg = 0; reg < 4; ++reg) inv[reg] = 1.0f / lrow[reg];
#pragma unroll
    for (int n = 0; n < 4; ++n) {
#pragma unroll
        for (int reg = 0; reg < 4; ++reg) {
            const size_t orow = rbase + qt * 64 + w * 16 + g * 4 + reg;
            Oa[orow * 1024 + cbase + n * 16 + fr] = f2bf(oacc[n][reg] * inv[reg]);
        }
    }
}

// ---------------------------------------------------------------------------
extern "C" void kernel_launch(void* const* d_in, const int* in_sizes, int n_in,
                              void* d_out, int out_size, void* d_ws, size_t ws_size,
                              hipStream_t stream) {
    const float* q  = (const float*)d_in[0];
    const float* k  = (const float*)d_in[1];
    const float* v  = (const float*)d_in[2];
    const float* wq = (const float*)d_in[3];
    const float* wk = (const float*)d_in[4];
    const float* wv = (const float*)d_in[5];
    const float* wo = (const float*)d_in[6];
    float* out = (float*)d_out;

    const size_t NTOK = 4096, DIM = 1024;
    unsigned short* Xq = (unsigned short*)d_ws;
    unsigned short* Xk = Xq + NTOK * DIM;
    unsigned short* Xv = Xk + NTOK * DIM;
    unsigned short* Oa = Xv + NTOK * DIM;   // 4 x 8 MB = 32 MB workspace

    proj3_kernel<<<dim3(8, 32, 3), 256, 0, stream>>>(q, k, v, wq, wk, wv, Xq, Xk, Xv);
    flash_attn_kernel<<<dim3(32, 32), 256, 0, stream>>>(Xq, Xk, Xv, Oa);
    outproj_kernel<<<dim3(8, 32), 256, 0, stream>>>(Oa, wo, out);
}

// Round 2
// 270.532 us; speedup vs baseline: 1.2901x; 1.2901x over previous
//
#include <hip/hip_runtime.h>
#include <stdint.h>

// MHA: B=2, S=2048, DIM=1024, H=16, HD=64, causal. fp32 I/O, bf16 MFMA internal.
// Pipeline: wconvert (weights->bf16) -> proj3 (Xq, Xk, Xvt[dim][token]) ->
//           flash (transposed-S scheme) -> outproj (fp32 out).

typedef short s16x8 __attribute__((ext_vector_type(8)));
typedef float f32x4 __attribute__((ext_vector_type(4)));

#define MFMA_BF16 __builtin_amdgcn_mfma_f32_16x16x32_bf16

static __device__ __forceinline__ unsigned short f2bf(float f) {
    union { float f; unsigned u; } x{f};
    unsigned r = x.u + 0x7fff + ((x.u >> 16) & 1);   // RNE
    return (unsigned short)(r >> 16);
}
static __device__ __forceinline__ unsigned pk2(float a, float b) {
    return (unsigned)f2bf(a) | ((unsigned)f2bf(b) << 16);
}

// async 16B global->LDS (dest must be wave-uniform base; lanes land at base+lane*16)
static __device__ __forceinline__ void ald16(unsigned short* lds, const unsigned short* g) {
    __builtin_amdgcn_global_load_lds(
        (const __attribute__((address_space(1))) unsigned int*)g,
        (__attribute__((address_space(3))) unsigned int*)lds, 16, 0, 0);
}

// ---------------------------------------------------------------------------
// wconvert: wq,wk,wv,wo fp32 [1M elems each] -> contiguous bf16 Wb[4M]
// ---------------------------------------------------------------------------
__global__ __launch_bounds__(256) void wconvert_kernel(
        const float* __restrict__ wq, const float* __restrict__ wk,
        const float* __restrict__ wv, const float* __restrict__ wo,
        unsigned short* __restrict__ Wb) {
    const size_t idx = ((size_t)blockIdx.x * 256 + threadIdx.x) * 8;
    const int region = (int)(idx >> 20);                 // 1048576 elems per weight
    const size_t off = idx & 1048575;
    const float* src = region == 0 ? wq : region == 1 ? wk : region == 2 ? wv : wo;
    const float4* p = (const float4*)(src + off);
    float4 a = p[0], b = p[1];
    uint4 u;
    u.x = pk2(a.x, a.y); u.y = pk2(a.z, a.w);
    u.z = pk2(b.x, b.y); u.w = pk2(b.z, b.w);
    *(uint4*)(Wb + idx) = u;
}

// ---------------------------------------------------------------------------
// proj3: C[4096 x 1024] = A_fp32 @ W_bf16^T.  128x128 tile, BK=32.
// A staged via VGPR (fp32->bf16, padded LDS); B via global_load_lds (unpadded).
// z==2 writes Xvt transposed [dim][token] with packed 8B stores.
// grid (8, 32, 3)
// ---------------------------------------------------------------------------
__global__ __launch_bounds__(256) void proj3_kernel(
        const float* __restrict__ q, const float* __restrict__ k, const float* __restrict__ v,
        const unsigned short* __restrict__ Wb,
        unsigned short* __restrict__ Xq, unsigned short* __restrict__ Xk,
        unsigned short* __restrict__ Xvt) {
    constexpr int Kd = 1024;
    __shared__ unsigned short lsA[128 * 40];   // padded 40 (80B rows) - VGPR-staged
    __shared__ unsigned short lsB[128 * 32];   // unpadded - global_load_lds

    const int z = blockIdx.z;
    const float* A = z == 0 ? q : z == 1 ? k : v;
    const unsigned short* Bw = Wb + (size_t)z * 1048576;

    const int t = threadIdx.x;
    const int m0 = blockIdx.y * 128, n0 = blockIdx.x * 128;
    const int w = t >> 6, lane = t & 63, fr = lane & 15, g = lane >> 4, fq = g * 8;
    const int wm = (w >> 1) * 64, wn = (w & 1) * 64;
    const int ar = t >> 1, ac = (t & 1) * 16;        // A staging
    const int br = t >> 2, bc = (t & 3) * 8;         // B staging (8 elems/lane)

    f32x4 acc[4][4] = {};

    for (int k0 = 0; k0 < Kd; k0 += 32) {
        // async B: 128x32 bf16 = 2 instrs/thread
        ald16(lsB + (size_t)w * 512,        Bw + (size_t)(n0 + br) * Kd + k0 + bc);
        ald16(lsB + 2048 + (size_t)w * 512, Bw + (size_t)(n0 + 64 + br) * Kd + k0 + bc);
        // A: fp32 -> bf16 via VGPR
        {
            const float4* pa = (const float4*)(A + (size_t)(m0 + ar) * Kd + k0 + ac);
            float4 a0 = pa[0], a1 = pa[1], a2 = pa[2], a3 = pa[3];
            uint4 u0, u1;
            u0.x = pk2(a0.x, a0.y); u0.y = pk2(a0.z, a0.w);
            u0.z = pk2(a1.x, a1.y); u0.w = pk2(a1.z, a1.w);
            u1.x = pk2(a2.x, a2.y); u1.y = pk2(a2.z, a2.w);
            u1.z = pk2(a3.x, a3.y); u1.w = pk2(a3.z, a3.w);
            *(uint4*)(lsA + ar * 40 + ac)     = u0;
            *(uint4*)(lsA + ar * 40 + ac + 8) = u1;
        }
        __syncthreads();

        s16x8 af[4], bfv[4];
#pragma unroll
        for (int mi = 0; mi < 4; ++mi)
            af[mi] = *(const s16x8*)(lsA + (wm + mi * 16 + fr) * 40 + fq);
#pragma unroll
        for (int ni = 0; ni < 4; ++ni)
            bfv[ni] = *(const s16x8*)(lsB + (wn + ni * 16 + fr) * 32 + fq);
#pragma unroll
        for (int mi = 0; mi < 4; ++mi)
#pragma unroll
            for (int ni = 0; ni < 4; ++ni)
                acc[mi][ni] = MFMA_BF16(af[mi], bfv[ni], acc[mi][ni], 0, 0, 0);
        __syncthreads();
    }

    if (z != 2) {
        unsigned short* C = z ? Xk : Xq;
#pragma unroll
        for (int mi = 0; mi < 4; ++mi)
#pragma unroll
            for (int ni = 0; ni < 4; ++ni)
#pragma unroll
                for (int reg = 0; reg < 4; ++reg)
                    C[(size_t)(m0 + wm + mi * 16 + g * 4 + reg) * 1024 +
                      n0 + wn + ni * 16 + fr] = f2bf(acc[mi][ni][reg]);
    } else {
        // transposed: Xvt[dim][token], pack 4 consecutive tokens (regs) per 8B store
#pragma unroll
        for (int mi = 0; mi < 4; ++mi)
#pragma unroll
            for (int ni = 0; ni < 4; ++ni) {
                uint2 u;
                u.x = pk2(acc[mi][ni][0], acc[mi][ni][1]);
                u.y = pk2(acc[mi][ni][2], acc[mi][ni][3]);
                *(uint2*)(Xvt + (size_t)(n0 + wn + ni * 16 + fr) * 4096 +
                          m0 + wm + mi * 16 + g * 4) = u;
            }
    }
}

// ---------------------------------------------------------------------------
// flash attention, transposed-S scheme. grid (32 qtiles desc, 32 b*h), 256 thr.
// Per wave: 16 q rows (q = n-dim = lane&15). S^T = K(A) x Q(B); O^T = Vt(A) x P(B).
// LDS tiles 64x64 bf16, XOR-swizzled 16B chunks (bank-optimal).
// ---------------------------------------------------------------------------
__global__ __launch_bounds__(256) void flash_attn_kernel(
        const unsigned short* __restrict__ Xq, const unsigned short* __restrict__ Xk,
        const unsigned short* __restrict__ Xvt, unsigned short* __restrict__ Oa) {
    __shared__ unsigned short Kls[64 * 64];
    __shared__ unsigned short Vls[64 * 64];
    __shared__ unsigned short Pls[4 * 16 * 64];

    const int t = threadIdx.x;
    const int qt = 31 - (int)blockIdx.x;       // descending work for LPT balance
    const int bh = blockIdx.y;
    const int b = bh >> 4, h = bh & 15;
    const size_t rbase = (size_t)b * 2048;
    const int cbase = h * 64;

    const int w = t >> 6, lane = t & 63, fr = lane & 15, g = lane >> 4, fq = g * 8;
    const int sr = t >> 2;                     // staging row 0..63
    const int c0 = (t & 3) * 2;                // staging chunk (of 8 elems)

    const int qrow = qt * 64 + w * 16 + fr;    // this lane's q (n-dim)
    unsigned short* Pw = Pls + w * 1024;       // per-wave 16x64 P scratch

    // Q B-fragments, loaded once
    const unsigned short* qp = Xq + (rbase + qrow) * 1024 + cbase;
    s16x8 qf0 = *(const s16x8*)(qp + fq);
    s16x8 qf1 = *(const s16x8*)(qp + 32 + fq);

    const float SCL = 0.125f * 1.44269504089f; // 1/sqrt(64) * log2(e); use exp2
    float m_i = -1e30f, l_i = 0.f;
    f32x4 oacc[4] = {};

    for (int kt = 0; kt <= qt; ++kt) {
        // ---- stage K [key][d] and Vt [d][key], both coalesced, swizzled ----
        {
            const unsigned short* kp = Xk + (rbase + kt * 64 + sr) * 1024 + cbase + c0 * 8;
            uint4 k0 = *(const uint4*)kp, k1 = *(const uint4*)(kp + 8);
            *(uint4*)(Kls + sr * 64 + ((c0 ^ (sr & 7)) * 8))       = k0;
            *(uint4*)(Kls + sr * 64 + (((c0 + 1) ^ (sr & 7)) * 8)) = k1;
            const unsigned short* vp = Xvt + (size_t)(cbase + sr) * 4096 +
                                       rbase + kt * 64 + c0 * 8;
            uint4 v0 = *(const uint4*)vp, v1 = *(const uint4*)(vp + 8);
            *(uint4*)(Vls + sr * 64 + ((c0 ^ (sr & 7)) * 8))       = v0;
            *(uint4*)(Vls + sr * 64 + (((c0 + 1) ^ (sr & 7)) * 8)) = v1;
        }
        __syncthreads();

        // ---- S^T frags: rows = keys (4 x 16), cols = q ----
        float p[4][4];
        float mloc = -1e30f;
#pragma unroll
        for (int m16 = 0; m16 < 4; ++m16) {
            const int krow = m16 * 16 + fr;
            s16x8 kf0 = *(const s16x8*)(Kls + krow * 64 + ((g ^ (fr & 7)) * 8));
            s16x8 kf1 = *(const s16x8*)(Kls + krow * 64 + (((4 + g) ^ (fr & 7)) * 8));
            f32x4 sf = {};
            sf = MFMA_BF16(kf0, qf0, sf, 0, 0, 0);
            sf = MFMA_BF16(kf1, qf1, sf, 0, 0, 0);
            if (kt == qt) {
#pragma unroll
                for (int r = 0; r < 4; ++r) {
                    const int keyg = kt * 64 + m16 * 16 + g * 4 + r;
                    const float x = sf[r] * SCL;
                    p[m16][r] = (keyg <= qrow) ? x : -1e30f;
                }
            } else {
#pragma unroll
                for (int r = 0; r < 4; ++r) p[m16][r] = sf[r] * SCL;
            }
#pragma unroll
            for (int r = 0; r < 4; ++r) mloc = fmaxf(mloc, p[m16][r]);
        }
        // cross-quad (lanes fr, fr+16, fr+32, fr+48 share a q-row)
        mloc = fmaxf(mloc, __shfl_xor(mloc, 16, 64));
        mloc = fmaxf(mloc, __shfl_xor(mloc, 32, 64));

        const float mn = fmaxf(m_i, mloc);
        const float alpha = exp2f(m_i - mn);
        m_i = mn;
        float s_loc = 0.f;
#pragma unroll
        for (int m16 = 0; m16 < 4; ++m16)
#pragma unroll
            for (int r = 0; r < 4; ++r) {
                const float e = exp2f(p[m16][r] - mn);
                p[m16][r] = e;
                s_loc += e;
            }
        s_loc += __shfl_xor(s_loc, 16, 64);
        s_loc += __shfl_xor(s_loc, 32, 64);
        l_i = l_i * alpha + s_loc;
#pragma unroll
        for (int n = 0; n < 4; ++n)
#pragma unroll
            for (int r = 0; r < 4; ++r) oacc[n][r] *= alpha;

        // ---- P: per-wave LDS round trip (packed b64 writes, swizzled) ----
#pragma unroll
        for (int m16 = 0; m16 < 4; ++m16) {
            uint2 u;
            u.x = pk2(p[m16][0], p[m16][1]);
            u.y = pk2(p[m16][2], p[m16][3]);
            const int ch = 2 * m16 + (g >> 1);
            *(uint2*)(Pw + fr * 64 + ((ch ^ (fr & 7)) * 8) + (g & 1) * 4) = u;
        }
        __asm__ __volatile__("" ::: "memory");   // keep write->read order (same wave)
        s16x8 pf0 = *(const s16x8*)(Pw + fr * 64 + ((g ^ (fr & 7)) * 8));
        s16x8 pf1 = *(const s16x8*)(Pw + fr * 64 + (((4 + g) ^ (fr & 7)) * 8));

        // ---- O^T += Vt(A) x P(B) ----
#pragma unroll
        for (int m16 = 0; m16 < 4; ++m16) {
            const int vrow = m16 * 16 + fr;
            s16x8 vf0 = *(const s16x8*)(Vls + vrow * 64 + ((g ^ (fr & 7)) * 8));
            s16x8 vf1 = *(const s16x8*)(Vls + vrow * 64 + (((4 + g) ^ (fr & 7)) * 8));
            oacc[m16] = MFMA_BF16(vf0, pf0, oacc[m16], 0, 0, 0);
            oacc[m16] = MFMA_BF16(vf1, pf1, oacc[m16], 0, 0, 0);
        }
        __syncthreads();
    }

    // ---- epilogue: O^T[d][q] -> Oa[token][dim], packed 8B stores ----
    const float inv = 1.0f / l_i;
#pragma unroll
    for (int m16 = 0; m16 < 4; ++m16) {
        uint2 u;
        u.x = pk2(oacc[m16][0] * inv, oacc[m16][1] * inv);
        u.y = pk2(oacc[m16][2] * inv, oacc[m16][3] * inv);
        *(uint2*)(Oa + (rbase + qrow) * 1024 + cbase + m16 * 16 + g * 4) = u;
    }
}

// ---------------------------------------------------------------------------
// outproj: out_fp32[4096 x 1024] = Oa_bf16 @ Wo_bf16^T. 64x128 tile, BK=32,
// full global_load_lds staging. grid (8, 64) = 512 blocks.
// ---------------------------------------------------------------------------
__global__ __launch_bounds__(256) void outproj_kernel(
        const unsigned short* __restrict__ Oa, const unsigned short* __restrict__ Wo,
        float* __restrict__ out) {
    constexpr int Kd = 1024;
    __shared__ unsigned short lsA[64 * 32];
    __shared__ unsigned short lsB[128 * 32];

    const int t = threadIdx.x;
    const int m0 = blockIdx.y * 64, n0 = blockIdx.x * 128;
    const int w = t >> 6, lane = t & 63, fr = lane & 15, g = lane >> 4, fq = g * 8;
    const int wm = (w >> 1) * 32, wn = (w & 1) * 64;
    const int br = t >> 2, bc = (t & 3) * 8;

    f32x4 acc[2][4] = {};

    for (int k0 = 0; k0 < Kd; k0 += 32) {
        ald16(lsA + (size_t)w * 512,        Oa + (size_t)(m0 + br) * Kd + k0 + bc);
        ald16(lsB + (size_t)w * 512,        Wo + (size_t)(n0 + br) * Kd + k0 + bc);
        ald16(lsB + 2048 + (size_t)w * 512, Wo + (size_t)(n0 + 64 + br) * Kd + k0 + bc);
        __syncthreads();

        s16x8 af[2], bfv[4];
#pragma unroll
        for (int mi = 0; mi < 2; ++mi)
            af[mi] = *(const s16x8*)(lsA + (wm + mi * 16 + fr) * 32 + fq);
#pragma unroll
        for (int ni = 0; ni < 4; ++ni)
            bfv[ni] = *(const s16x8*)(lsB + (wn + ni * 16 + fr) * 32 + fq);
#pragma unroll
        for (int mi = 0; mi < 2; ++mi)
#pragma unroll
            for (int ni = 0; ni < 4; ++ni)
                acc[mi][ni] = MFMA_BF16(af[mi], bfv[ni], acc[mi][ni], 0, 0, 0);
        __syncthreads();
    }

#pragma unroll
    for (int mi = 0; mi < 2; ++mi)
#pragma unroll
        for (int ni = 0; ni < 4; ++ni)
#pragma unroll
            for (int reg = 0; reg < 4; ++reg)
                out[(size_t)(m0 + wm + mi * 16 + g * 4 + reg) * 1024 +
                    n0 + wn + ni * 16 + fr] = acc[mi][ni][reg];
}

// ---------------------------------------------------------------------------
extern "C" void kernel_launch(void* const* d_in, const int* in_sizes, int n_in,
                              void* d_out, int out_size, void* d_ws, size_t ws_size,
                              hipStream_t stream) {
    const float* q  = (const float*)d_in[0];
    const float* k  = (const float*)d_in[1];
    const float* v  = (const float*)d_in[2];
    const float* wq = (const float*)d_in[3];
    const float* wk = (const float*)d_in[4];
    const float* wv = (const float*)d_in[5];
    const float* wo = (const float*)d_in[6];
    float* out = (float*)d_out;

    // workspace: Wb 8MB | Xq 8MB | Xk 8MB | Xvt 8MB | Oa 8MB  (40MB total)
    unsigned short* Wb  = (unsigned short*)d_ws;
    unsigned short* Xq  = Wb  + 4 * 1048576;
    unsigned short* Xk  = Xq  + 4194304;
    unsigned short* Xvt = Xk  + 4194304;
    unsigned short* Oa  = Xvt + 4194304;

    wconvert_kernel<<<2048, 256, 0, stream>>>(wq, wk, wv, wo, Wb);
    proj3_kernel<<<dim3(8, 32, 3), 256, 0, stream>>>(q, k, v, Wb, Xq, Xk, Xvt);
    flash_attn_kernel<<<dim3(32, 32), 256, 0, stream>>>(Xq, Xk, Xvt, Oa);
    outproj_kernel<<<dim3(8, 64), 256, 0, stream>>>(Oa, Wb + 3 * 1048576, out);
}